// Round 2
// baseline (213.047 us; speedup 1.0000x reference)
//
#include <hip/hip_runtime.h>
#include <hip/hip_bf16.h>

// ConformerAttention on MI355X (gfx950)
// B=2 T=2048 D=512 NH=8 DK=64 P=4095
//
// rel_shift identity: scores_bd[t,s] = q_v[t] . pos[s - t + 2047]
// -> banded GEMM with rolling 128-slot ring (each band column computed once).

typedef __attribute__((ext_vector_type(8))) short short8;
typedef __attribute__((ext_vector_type(16))) float f32x16;
typedef __attribute__((ext_vector_type(4))) float f32x4;

static __device__ __forceinline__ unsigned short f2bf(float x) {
    unsigned int u = __builtin_bit_cast(unsigned int, x);
    u += 0x7FFFu + ((u >> 16) & 1u);   // RNE
    return (unsigned short)(u >> 16);
}
static __device__ __forceinline__ unsigned int pack2bf(float lo, float hi) {
    return (unsigned int)f2bf(lo) | ((unsigned int)f2bf(hi) << 16);
}
static __device__ __forceinline__ f32x16 zero16() {
    f32x16 v;
#pragma unroll
    for (int i = 0; i < 16; ++i) v[i] = 0.0f;
    return v;
}
static __device__ __forceinline__ f32x16 mfma_bf(short8 a, short8 b, f32x16 c) {
    return __builtin_amdgcn_mfma_f32_32x32x16_bf16(a, b, c, 0, 0, 0);
}

// ---------------------------------------------------------------- cvt fp32->bf16
__global__ void cvt_bf16_kernel(const float* __restrict__ src,
                                unsigned short* __restrict__ dst, int n4) {
    int i = blockIdx.x * blockDim.x + threadIdx.x;
    int stride = gridDim.x * blockDim.x;
    for (; i < n4; i += stride) {
        float4 v = ((const float4*)src)[i];
        uint2 o;
        o.x = pack2bf(v.x, v.y);
        o.y = pack2bf(v.z, v.w);
        ((uint2*)dst)[i] = o;
    }
}

// ---------------------------------------------------------------- GEMM C = A @ B^T
// A: M x 512 bf16 row-major, Bw: N x 512 bf16 row-major, K = 512 fixed.
// tile 128x128, 4 waves (2x2 of 64x64), 32x32x16 MFMA, BK=32, swizzled LDS.
// EPI 0: QKV epilogue (writes qu,qv,k,v in (b,h,t,dk) with biases)
// EPI 1: pos epilogue (writes (h,p,dk), guard p<4095)
// EPI 2: plain fp32 store to out (row-major M x 512)
template<int EPI>
__global__ __launch_bounds__(256) void gemm_bt(
    const unsigned short* __restrict__ A, const unsigned short* __restrict__ Bw,
    int M,
    unsigned short* __restrict__ o0, unsigned short* __restrict__ o1,
    unsigned short* __restrict__ o2, unsigned short* __restrict__ o3,
    float* __restrict__ o_f,
    const float* __restrict__ bu, const float* __restrict__ bv)
{
    __shared__ __align__(16) unsigned short As[128 * 32];
    __shared__ __align__(16) unsigned short Bs[128 * 32];

    const int tid = threadIdx.x;
    const int lane = tid & 63;
    const int l31 = lane & 31;
    const int h = (lane >> 5) & 1;
    const int wid = tid >> 6;
    const int wm = wid >> 1, wn = wid & 1;
    const int m0 = blockIdx.y * 128, n0 = blockIdx.x * 128;

    f32x16 acc[2][2];
#pragma unroll
    for (int mt = 0; mt < 2; ++mt)
#pragma unroll
        for (int nt = 0; nt < 2; ++nt) acc[mt][nt] = zero16();

    const int row_s = tid >> 2;   // 0..63
    const int q_s = tid & 3;      // 8-elem chunk

#pragma unroll 1
    for (int k0 = 0; k0 < 512; k0 += 32) {
        __syncthreads();
#pragma unroll
        for (int rep = 0; rep < 2; ++rep) {
            int row = row_s + rep * 64;
            int ar = m0 + row; if (ar > M - 1) ar = M - 1;
            short8 av = *(const short8*)(A + (size_t)ar * 512 + k0 + q_s * 8);
            *(short8*)((char*)As + ((row * 64 + q_s * 16) ^ ((row & 3) << 4))) = av;
            int br = n0 + row;
            short8 bv8 = *(const short8*)(Bw + (size_t)br * 512 + k0 + q_s * 8);
            *(short8*)((char*)Bs + ((row * 64 + q_s * 16) ^ ((row & 3) << 4))) = bv8;
        }
        __syncthreads();

        short8 af[2][2], bf[2][2];
#pragma unroll
        for (int mt = 0; mt < 2; ++mt)
#pragma unroll
            for (int ks = 0; ks < 2; ++ks) {
                int row = wm * 64 + mt * 32 + l31;
                af[mt][ks] = *(const short8*)((char*)As +
                    ((row * 64 + ks * 32 + h * 16) ^ ((row & 3) << 4)));
            }
#pragma unroll
        for (int nt = 0; nt < 2; ++nt)
#pragma unroll
            for (int ks = 0; ks < 2; ++ks) {
                int row = wn * 64 + nt * 32 + l31;
                bf[nt][ks] = *(const short8*)((char*)Bs +
                    ((row * 64 + ks * 32 + h * 16) ^ ((row & 3) << 4)));
            }
#pragma unroll
        for (int mt = 0; mt < 2; ++mt)
#pragma unroll
            for (int nt = 0; nt < 2; ++nt)
#pragma unroll
                for (int ks = 0; ks < 2; ++ks)
                    acc[mt][nt] = mfma_bf(af[mt][ks], bf[nt][ks], acc[mt][nt]);
    }

    // epilogue  (C layout: col = l31, row = (r&3) + 8*(r>>2) + 4*h)
#pragma unroll
    for (int mt = 0; mt < 2; ++mt)
#pragma unroll
        for (int nt = 0; nt < 2; ++nt) {
            int Ncol = n0 + wn * 64 + nt * 32 + l31;
#pragma unroll
            for (int r = 0; r < 16; ++r) {
                int Mrow = m0 + wm * 64 + mt * 32 + (r & 3) + ((r >> 2) << 3) + h * 4;
                float v = acc[mt][nt][r];
                if (EPI == 0) {
                    int b = Mrow >> 11, t = Mrow & 2047;
                    int sec = Ncol >> 9, hd = (Ncol >> 6) & 7, dk = Ncol & 63;
                    size_t idx = ((size_t)((b * 8 + hd) * 2048 + t)) * 64 + dk;
                    if (sec == 0) {
                        o0[idx] = f2bf(v + bu[hd * 64 + dk]);
                        o1[idx] = f2bf(v + bv[hd * 64 + dk]);
                    } else if (sec == 1) {
                        o2[idx] = f2bf(v);
                    } else {
                        o3[idx] = f2bf(v);
                    }
                } else if (EPI == 1) {
                    if (Mrow < M) {
                        int hd = Ncol >> 6, dk = Ncol & 63;
                        o0[((size_t)(hd * 4095 + Mrow)) * 64 + dk] = f2bf(v);
                    }
                } else {
                    o_f[(size_t)Mrow * 512 + Ncol] = v;
                }
            }
        }
}

// ---------------------------------------------------------------- fused attention
// grid (32 t-blocks, 16 bh). 128 threads = 2 waves, wave owns 32 t-rows.
// Swapped-operand: S^T = mfma(K, Q^T). NOTE 32x32 C/D layout: lanes l and l+32
// share the same t column (col=lane&31), each holding interleaved halves of the
// s-range -> softmax stats must be combined across the lane^32 pair.
__global__ __launch_bounds__(128) void attn_kernel(
    const unsigned short* __restrict__ qup, const unsigned short* __restrict__ qvp,
    const unsigned short* __restrict__ kp,  const unsigned short* __restrict__ vp,
    const unsigned short* __restrict__ posp,
    const unsigned char* __restrict__ maskp,
    unsigned short* __restrict__ attnp)
{
    const int tb = blockIdx.x, bh = blockIdx.y;
    const int b = bh >> 3, head = bh & 7;
    const int t0 = tb * 64;

    const int lane = threadIdx.x & 63;
    const int l31 = lane & 31;
    const int h = (lane >> 5) & 1;
    const int h4 = h * 4;
    const int wid = threadIdx.x >> 6;    // 0,1

    __shared__ __align__(16) unsigned short Kss[64 * 64];
    __shared__ __align__(16) unsigned short Vts[64 * 64];   // transposed V: [dk][s]
    __shared__ __align__(16) unsigned short Pss[64 * 64];   // pos chunk [r_local][dk]
    __shared__ __align__(16) float Ew[2 * 32 * 132];        // per-wave ring [t(l31)][slot 0..127]
    __shared__ __align__(8)  unsigned int Msk[128];         // 64 rows x 2 halves

    const unsigned short* posg = posp + (size_t)head * 4095 * 64;

    // Q fragments (B-operand layout: n=t=l31, k = 16*ks + 8*h + j) -- loaded once
    const size_t qoff = ((size_t)bh * 2048 + t0 + wid * 32 + l31) * 64;
    short8 qu_f[4], qv_f[4];
#pragma unroll
    for (int ks = 0; ks < 4; ++ks) {
        qu_f[ks] = *(const short8*)(qup + qoff + ks * 16 + h * 8);
        qv_f[ks] = *(const short8*)(qvp + qoff + ks * 16 + h * 8);
    }

    float* ewp = Ew + wid * (32 * 132) + l31 * 132;

    auto stage_pos = [&](int c_r0) {
#pragma unroll
        for (int rep = 0; rep < 4; ++rep) {
            int idx = threadIdx.x + rep * 128;
            int row = idx >> 3, q = idx & 7;
            int r = c_r0 + row;
            short8 pv8;
            if ((unsigned)r < 4095u) {
                pv8 = *(const short8*)(posg + (size_t)r * 64 + q * 8);
            } else {
#pragma unroll
                for (int j = 0; j < 8; ++j) pv8[j] = 0;
            }
            *(short8*)((char*)Pss + ((row * 128 + q * 16) ^ ((row & 7) << 4))) = pv8;
        }
    };

    // E^T = pos_chunk @ Qv^T : D[r, t], lane col = t, rows = slots. Lane pair
    // (l31, l31+32) shares ewp and writes disjoint slot subsets.
    auto e_gemm = [&](int slotb) {
#pragma unroll
        for (int et = 0; et < 2; ++et) {
            f32x16 ea = zero16();
#pragma unroll
            for (int ks = 0; ks < 4; ++ks) {
                int row = et * 32 + l31;
                short8 a = *(const short8*)((char*)Pss +
                    ((row * 128 + ks * 32 + h * 16) ^ ((row & 7) << 4)));
                ea = mfma_bf(a, qv_f[ks], ea);
            }
#pragma unroll
            for (int qd = 0; qd < 4; ++qd) {
                f32x4 w;
                w[0] = ea[qd * 4 + 0]; w[1] = ea[qd * 4 + 1];
                w[2] = ea[qd * 4 + 2]; w[3] = ea[qd * 4 + 3];
                *(f32x4*)(ewp + slotb + et * 32 + qd * 8 + h4) = w;
            }
        }
    };

    // prologue: fill ring slots for r in [1984-t0, 1984-t0+128)
    stage_pos(1984 - t0);
    __syncthreads();
    e_gemm((4032 - t0) & 127);
    __syncthreads();
    stage_pos(2048 - t0);
    __syncthreads();
    e_gemm((4096 - t0) & 127);

    float m = -3.0e38f, lsum = 0.0f;
    f32x16 o_acc[2];
    o_acc[0] = zero16(); o_acc[1] = zero16();

    const unsigned short* kg0 = kp + (size_t)bh * 2048 * 64;
    const unsigned short* vg0 = vp + (size_t)bh * 2048 * 64;

#pragma unroll 1
    for (int it = 0; it < 32; ++it) {
        const int s0 = it * 64;
        __syncthreads();
        // ---- stage K, V^T, mask, next pos chunk
        const unsigned short* kg = kg0 + (size_t)s0 * 64;
        const unsigned short* vg = vg0 + (size_t)s0 * 64;
#pragma unroll
        for (int rep = 0; rep < 4; ++rep) {
            int idx = threadIdx.x + rep * 128;
            int row = idx >> 3, q = idx & 7;
            short8 kv = *(const short8*)(kg + row * 64 + q * 8);
            *(short8*)((char*)Kss + ((row * 128 + q * 16) ^ ((row & 7) << 4))) = kv;
        }
#pragma unroll
        for (int rep = 0; rep < 4; ++rep) {
            int idx = threadIdx.x + rep * 128;
            int s = idx & 63, c = idx >> 6;
            short8 vv = *(const short8*)(vg + s * 64 + c * 8);
#pragma unroll
            for (int j = 0; j < 8; ++j) {
                int row = c * 8 + j;
                *(unsigned short*)((char*)Vts + (row * 128 + ((2 * s) ^ (j << 4)))) =
                    (unsigned short)vv[j];
            }
        }
        {
            int row = threadIdx.x & 63, half = threadIdx.x >> 6;
            const unsigned char* mp = maskp +
                ((size_t)(b * 2048 + t0 + row)) * 2048 + s0 + half * 32;
            uint4 aa = *(const uint4*)mp;
            uint4 bb = *(const uint4*)(mp + 16);
            auto nz4 = [](unsigned int x) -> unsigned int {
                x |= x >> 4; x |= x >> 2; x |= x >> 1;
                x &= 0x01010101u;
                return (x & 1u) | ((x >> 7) & 2u) | ((x >> 14) & 4u) | ((x >> 21) & 8u);
            };
            Msk[row * 2 + half] =
                nz4(aa.x) | (nz4(aa.y) << 4) | (nz4(aa.z) << 8) | (nz4(aa.w) << 12) |
                (nz4(bb.x) << 16) | (nz4(bb.y) << 20) | (nz4(bb.z) << 24) | (nz4(bb.w) << 28);
        }
        if (it < 31) stage_pos(2112 - t0 + 64 * it);
        __syncthreads();

        // ---- S^T = K . Qu^T  (2 s-subtiles x 4 k-steps)
        f32x16 sacc[2];
        sacc[0] = zero16(); sacc[1] = zero16();
#pragma unroll
        for (int st = 0; st < 2; ++st)
#pragma unroll
            for (int ks = 0; ks < 4; ++ks) {
                int row = st * 32 + l31;
                short8 a = *(const short8*)((char*)Kss +
                    ((row * 128 + ks * 32 + h * 16) ^ ((row & 7) << 4)));
                sacc[st] = mfma_bf(a, qu_f[ks], sacc[st]);
            }

        // ---- gather BD from ring, scale, mask
        unsigned long long mw = ((const unsigned long long*)Msk)[wid * 32 + l31];
        const int sbase = s0 - t0 - wid * 32 - l31 + 4095;  // slot = (r mod 128)
        float sv[32];
#pragma unroll
        for (int st = 0; st < 2; ++st)
#pragma unroll
            for (int r = 0; r < 16; ++r) {
                int s_loc = st * 32 + (r & 3) + ((r >> 2) << 3) + h4;
                float bd = ewp[(sbase + s_loc) & 127];
                sv[st * 16 + r] = (sacc[st][r] + bd) * 0.125f;
            }
        if (mw != 0ull) {
#pragma unroll
            for (int st = 0; st < 2; ++st)
#pragma unroll
                for (int r = 0; r < 16; ++r) {
                    int s_loc = st * 32 + (r & 3) + ((r >> 2) << 3) + h4;
                    if ((mw >> s_loc) & 1ull)
                        sv[st * 16 + r] = sacc[st][r] * 0.125f - 100000.0f;
                }
        }

        // ---- online softmax over the full 64-wide tile row.
        // Lane pair (l31, l31+32) shares t: combine stats across ^32.
        float mx = sv[0];
#pragma unroll
        for (int i = 1; i < 32; ++i) mx = fmaxf(mx, sv[i]);
        mx = fmaxf(mx, __shfl_xor(mx, 32));          // pair-combined max
        float mnew = fmaxf(m, mx);
        float alpha = __expf(m - mnew);
        m = mnew;
        float psum = 0.0f;
#pragma unroll
        for (int i = 0; i < 32; ++i) { sv[i] = __expf(sv[i] - mnew); psum += sv[i]; }
        psum += __shfl_xor(psum, 32);                // pair-combined sum
        lsum = lsum * alpha + psum;
        o_acc[0] = o_acc[0] * alpha;
        o_acc[1] = o_acc[1] * alpha;

        // ---- pack P^T into B-fragments (lane-half exchange via shfl_xor 32)
        short8 pfrag[4];
#pragma unroll
        for (int st = 0; st < 2; ++st) {
            unsigned int X[8];
#pragma unroll
            for (int qd = 0; qd < 4; ++qd) {
                X[qd * 2 + 0] = pack2bf(sv[st * 16 + qd * 4 + 0], sv[st * 16 + qd * 4 + 1]);
                X[qd * 2 + 1] = pack2bf(sv[st * 16 + qd * 4 + 2], sv[st * 16 + qd * 4 + 3]);
            }
#pragma unroll
            for (int f = 0; f < 2; ++f) {
                unsigned int a0 = X[(2 * f) * 2 + 0], a1 = X[(2 * f) * 2 + 1];
                unsigned int b0 = X[(2 * f + 1) * 2 + 0], b1 = X[(2 * f + 1) * 2 + 1];
                unsigned int sa0 = (unsigned int)__shfl_xor((int)a0, 32);
                unsigned int sa1 = (unsigned int)__shfl_xor((int)a1, 32);
                unsigned int sb0 = (unsigned int)__shfl_xor((int)b0, 32);
                unsigned int sb1 = (unsigned int)__shfl_xor((int)b1, 32);
                union { unsigned int u[4]; short8 s8; } uu;
                uu.u[0] = h ? sb0 : a0;
                uu.u[1] = h ? sb1 : a1;
                uu.u[2] = h ? b0 : sa0;
                uu.u[3] = h ? b1 : sa1;
                pfrag[st * 2 + f] = uu.s8;
            }
        }

        // ---- O^T += V^T . P^T
#pragma unroll
        for (int dkt = 0; dkt < 2; ++dkt)
#pragma unroll
            for (int f = 0; f < 4; ++f) {
                int row = dkt * 32 + l31;
                short8 a = *(const short8*)((char*)Vts +
                    ((row * 128 + f * 32 + h * 16) ^ ((row & 7) << 4)));
                o_acc[dkt] = mfma_bf(a, pfrag[f], o_acc[dkt]);
            }

        // ---- compute next ring chunk (reads this iter's Pss; ring is pair-shared, same wave)
        if (it < 31) e_gemm((4160 - t0 + 64 * it) & 127);
    }

    // ---- epilogue: O^T[dk][t], lane col = t
    float inv = 1.0f / lsum;
    if (m <= -9.0e4f) inv = 0.0f;   // fully-masked row -> 0
    size_t obase = ((size_t)(b * 2048 + t0 + wid * 32 + l31)) * 512 + (size_t)head * 64;
#pragma unroll
    for (int dkt = 0; dkt < 2; ++dkt)
#pragma unroll
        for (int r = 0; r < 16; ++r) {
            int dk = dkt * 32 + (r & 3) + ((r >> 2) << 3) + h4;
            attnp[obase + dk] = f2bf(o_acc[dkt][r] * inv);
        }
}

// ---------------------------------------------------------------- host
extern "C" void kernel_launch(void* const* d_in, const int* in_sizes, int n_in,
                              void* d_out, int out_size, void* d_ws, size_t ws_size,
                              hipStream_t stream) {
    const float* x    = (const float*)d_in[0];
    const float* pe   = (const float*)d_in[1];
    const unsigned char* mask = (const unsigned char*)d_in[2];
    const float* wqkv = (const float*)d_in[3];
    const float* wpos = (const float*)d_in[4];
    const float* wout = (const float*)d_in[5];
    const float* bu   = (const float*)d_in[6];
    const float* bv   = (const float*)d_in[7];
    float* out = (float*)d_out;

    char* ws = (char*)d_ws;
    unsigned short* x_bf    = (unsigned short*)(ws + 0);
    unsigned short* pe_bf   = (unsigned short*)(ws + 4194304);
    unsigned short* wqkv_bf = (unsigned short*)(ws + 8388608);
    unsigned short* wpos_bf = (unsigned short*)(ws + 9961472);
    unsigned short* wout_bf = (unsigned short*)(ws + 10485760);
    unsigned short* qu      = (unsigned short*)(ws + 11010048);
    unsigned short* qv      = (unsigned short*)(ws + 15204352);
    unsigned short* kb      = (unsigned short*)(ws + 19398656);
    unsigned short* vb      = (unsigned short*)(ws + 23592960);
    unsigned short* posb    = (unsigned short*)(ws + 27787264);
    unsigned short* attnb   = (unsigned short*)(ws + 31981568);
    // total ws use: ~36.2 MB

    cvt_bf16_kernel<<<2048, 256, 0, stream>>>(x, x_bf, 2097152 / 4);
    cvt_bf16_kernel<<<2048, 256, 0, stream>>>(pe, pe_bf, 2096640 / 4);
    cvt_bf16_kernel<<<768, 256, 0, stream>>>(wqkv, wqkv_bf, 786432 / 4);
    cvt_bf16_kernel<<<256, 256, 0, stream>>>(wpos, wpos_bf, 262144 / 4);
    cvt_bf16_kernel<<<256, 256, 0, stream>>>(wout, wout_bf, 262144 / 4);

    gemm_bt<0><<<dim3(12, 32), 256, 0, stream>>>(x_bf, wqkv_bf, 4096,
        qu, qv, kb, vb, nullptr, bu, bv);
    gemm_bt<1><<<dim3(4, 32), 256, 0, stream>>>(pe_bf, wpos_bf, 4095,
        posb, nullptr, nullptr, nullptr, nullptr, nullptr, nullptr);

    attn_kernel<<<dim3(32, 16), 128, 0, stream>>>(qu, qv, kb, vb, posb, mask, attnb);

    gemm_bt<2><<<dim3(4, 32), 256, 0, stream>>>(attnb, wout_bf, 4096,
        nullptr, nullptr, nullptr, nullptr, out, nullptr, nullptr);
}

// Round 5
// 179.140 us; speedup vs baseline: 1.1893x; 1.1893x over previous
//
#include <hip/hip_runtime.h>
#include <hip/hip_bf16.h>

// ConformerAttention on MI355X (gfx950)
// B=2 T=2048 D=512 NH=8 DK=64 P=4095
// rel_shift identity: scores_bd[t,s] = q_v[t] . pos[s - t + 2047]
// -> banded GEMM with rolling 128-slot f32 ring (each band column computed once).
// R5: bisect round. Structural: s-split x2 + combine, V^T, maskw, direct pos
// loads, explicit swizzled staging, corrected pack. Numerics reverted to
// R2-proven: pack2bf (no asm cvt_pk), f32 ring, __expf*0.125, launch_bounds(128).

typedef __attribute__((ext_vector_type(8))) short short8;
typedef __attribute__((ext_vector_type(16))) float f32x16;
typedef __attribute__((ext_vector_type(4))) float f32x4;
typedef __attribute__((ext_vector_type(2))) unsigned int uint2v;

static __device__ __forceinline__ unsigned short f2bf(float x) {
    unsigned int u = __builtin_bit_cast(unsigned int, x);
    u += 0x7FFFu + ((u >> 16) & 1u);   // RNE
    return (unsigned short)(u >> 16);
}
static __device__ __forceinline__ unsigned int pack2bf(float lo, float hi) {
    return (unsigned int)f2bf(lo) | ((unsigned int)f2bf(hi) << 16);
}
static __device__ __forceinline__ float bf2f(unsigned short u) {
    return __builtin_bit_cast(float, (unsigned int)u << 16);
}
static __device__ __forceinline__ f32x16 zero16() {
    f32x16 v;
#pragma unroll
    for (int i = 0; i < 16; ++i) v[i] = 0.0f;
    return v;
}
static __device__ __forceinline__ f32x16 mfma_bf(short8 a, short8 b, f32x16 c) {
    return __builtin_amdgcn_mfma_f32_32x32x16_bf16(a, b, c, 0, 0, 0);
}

// ---------------------------------------------------------------- mask words
// words[(b*2048+t)*32 + itg] bit s_loc = mask[b][t][itg*64 + s_loc]
__global__ void maskw_kernel(const unsigned char* __restrict__ mask,
                             unsigned long long* __restrict__ words) {
    int idx = blockIdx.x * 256 + threadIdx.x;
    const unsigned long long* row =
        (const unsigned long long*)(mask + (size_t)(idx >> 5) * 2048) + (size_t)(idx & 31) * 8;
    unsigned long long w = 0;
#pragma unroll
    for (int k = 0; k < 8; ++k) {
        unsigned long long v = row[k];
        v |= v >> 4; v |= v >> 2; v |= v >> 1;
        v &= 0x0101010101010101ull;
        w |= ((v * 0x0102040810204080ull) >> 56) << (k * 8);
    }
    words[idx] = w;
}

// ---------------------------------------------------------------- GEMM C = A @ B^T
// K = 512. tile 128x128, 4 waves, 32x32x16 MFMA, BK=32, swizzled LDS.
// EPI 0: QKV epilogue -> qu,qv (+biases), k, v-transposed
// EPI 1: pos epilogue -> (h,p,dk), guard p<4095
// EPI 2: plain f32 store (row-major M x 512)
template<bool F32>
static __device__ __forceinline__ short8 load8(const void* base, size_t eoff) {
    if constexpr (F32) {
        const float4* p = (const float4*)((const float*)base + eoff);
        float4 a = p[0], b = p[1];
        union { unsigned int u[4]; short8 s; } r;
        r.u[0] = pack2bf(a.x, a.y);
        r.u[1] = pack2bf(a.z, a.w);
        r.u[2] = pack2bf(b.x, b.y);
        r.u[3] = pack2bf(b.z, b.w);
        return r.s;
    } else {
        return *(const short8*)((const unsigned short*)base + eoff);
    }
}

template<int EPI, bool AF32, bool BF32>
__global__ __launch_bounds__(256) void gemm_bt(
    const void* __restrict__ A, const void* __restrict__ Bw, int M,
    unsigned short* __restrict__ o0, unsigned short* __restrict__ o1,
    unsigned short* __restrict__ o2, unsigned short* __restrict__ o3,
    float* __restrict__ o_f,
    const float* __restrict__ bu, const float* __restrict__ bv)
{
    __shared__ __align__(16) unsigned short As[128 * 32];
    __shared__ __align__(16) unsigned short Bs[128 * 32];

    const int tid = threadIdx.x;
    const int lane = tid & 63;
    const int l31 = lane & 31;
    const int h = (lane >> 5) & 1;
    const int wid = tid >> 6;
    const int wm = wid >> 1, wn = wid & 1;
    const int m0 = blockIdx.y * 128, n0 = blockIdx.x * 128;

    f32x16 acc[2][2];
#pragma unroll
    for (int mt = 0; mt < 2; ++mt)
#pragma unroll
        for (int nt = 0; nt < 2; ++nt) acc[mt][nt] = zero16();

    const int row_s = tid >> 2;
    const int q_s = tid & 3;

#pragma unroll 1
    for (int k0 = 0; k0 < 512; k0 += 32) {
        __syncthreads();
#pragma unroll
        for (int rep = 0; rep < 2; ++rep) {
            int row = row_s + rep * 64;
            int ar = m0 + row; if (ar > M - 1) ar = M - 1;
            short8 av = load8<AF32>(A, (size_t)ar * 512 + k0 + q_s * 8);
            *(short8*)((char*)As + ((row * 64 + q_s * 16) ^ ((row & 3) << 4))) = av;
            int br = n0 + row;
            short8 bv8 = load8<BF32>(Bw, (size_t)br * 512 + k0 + q_s * 8);
            *(short8*)((char*)Bs + ((row * 64 + q_s * 16) ^ ((row & 3) << 4))) = bv8;
        }
        __syncthreads();

        short8 af[2][2], bf[2][2];
#pragma unroll
        for (int mt = 0; mt < 2; ++mt)
#pragma unroll
            for (int ks = 0; ks < 2; ++ks) {
                int row = wm * 64 + mt * 32 + l31;
                af[mt][ks] = *(const short8*)((char*)As +
                    ((row * 64 + ks * 32 + h * 16) ^ ((row & 3) << 4)));
            }
#pragma unroll
        for (int nt = 0; nt < 2; ++nt)
#pragma unroll
            for (int ks = 0; ks < 2; ++ks) {
                int row = wn * 64 + nt * 32 + l31;
                bf[nt][ks] = *(const short8*)((char*)Bs +
                    ((row * 64 + ks * 32 + h * 16) ^ ((row & 3) << 4)));
            }
#pragma unroll
        for (int mt = 0; mt < 2; ++mt)
#pragma unroll
            for (int nt = 0; nt < 2; ++nt)
#pragma unroll
                for (int ks = 0; ks < 2; ++ks)
                    acc[mt][nt] = mfma_bf(af[mt][ks], bf[nt][ks], acc[mt][nt]);
    }

#pragma unroll
    for (int mt = 0; mt < 2; ++mt)
#pragma unroll
        for (int nt = 0; nt < 2; ++nt) {
            int Ncol = n0 + wn * 64 + nt * 32 + l31;
#pragma unroll
            for (int r = 0; r < 16; ++r) {
                int Mrow = m0 + wm * 64 + mt * 32 + (r & 3) + ((r >> 2) << 3) + h * 4;
                float v = acc[mt][nt][r];
                if (EPI == 0) {
                    int b = Mrow >> 11, t = Mrow & 2047;
                    int sec = Ncol >> 9, hd = (Ncol >> 6) & 7, dk = Ncol & 63;
                    if (sec == 0) {
                        size_t idx = ((size_t)((b * 8 + hd) * 2048 + t)) * 64 + dk;
                        o0[idx] = f2bf(v + bu[hd * 64 + dk]);
                        o1[idx] = f2bf(v + bv[hd * 64 + dk]);
                    } else if (sec == 1) {
                        o2[((size_t)((b * 8 + hd) * 2048 + t)) * 64 + dk] = f2bf(v);
                    } else {
                        // v transposed: vt[bh][dk][t]
                        o3[((size_t)((b * 8 + hd) * 64 + dk)) * 2048 + t] = f2bf(v);
                    }
                } else if (EPI == 1) {
                    if (Mrow < M) {
                        int hd = Ncol >> 6, dk = Ncol & 63;
                        o0[((size_t)(hd * 4095 + Mrow)) * 64 + dk] = f2bf(v);
                    }
                } else {
                    o_f[(size_t)Mrow * 512 + Ncol] = v;
                }
            }
        }
}

// ---------------------------------------------------------------- fused attention
// grid (32 tb, 16 bh, 2 sc). 128 threads = 2 waves; wave owns 32 t-rows,
// block sweeps s in [sc, sc+1024). Swapped-operand S^T = mfma(K, Q^T);
// lane pair (l31, l31+32) shares a t-row (32x32 C/D: col=lane&31).
__global__ __launch_bounds__(128) void attn_kernel(
    const unsigned short* __restrict__ qup, const unsigned short* __restrict__ qvp,
    const unsigned short* __restrict__ kp,  const unsigned short* __restrict__ vtp,
    const unsigned short* __restrict__ posp,
    const unsigned long long* __restrict__ mwp,
    unsigned short* __restrict__ opart,
    float* __restrict__ mstat, float* __restrict__ lstat)
{
    const int tb = blockIdx.x, bh = blockIdx.y, scb = blockIdx.z;
    const int b = bh >> 3, head = bh & 7;
    const int t0 = tb * 64;
    const int sc = scb << 10;

    const int lane = threadIdx.x & 63;
    const int l31 = lane & 31;
    const int h = (lane >> 5) & 1;
    const int h4 = h * 4;
    const int wid = threadIdx.x >> 6;

    __shared__ __align__(16) unsigned short Kss[64 * 64];
    __shared__ __align__(16) unsigned short Vts[64 * 64];
    __shared__ __align__(16) float Ew[2 * 32 * 132];   // per-wave f32 ring [t][slot]

    const unsigned short* posg = posp + (size_t)head * 4095 * 64;
    const unsigned short* kg0 = kp + (size_t)bh * 2048 * 64;
    const unsigned short* vtg = vtp + (size_t)bh * 64 * 2048;
    const int t = t0 + wid * 32 + l31;

    // Q fragments (B-operand: col = t, k = ks*16 + h*8 + j)
    const size_t qoff = ((size_t)bh * 2048 + t) * 64;
    short8 qu_f[4], qv_f[4];
#pragma unroll
    for (int ks = 0; ks < 4; ++ks) {
        qu_f[ks] = *(const short8*)(qup + qoff + ks * 16 + h * 8);
        qv_f[ks] = *(const short8*)(qvp + qoff + ks * 16 + h * 8);
    }

    float* ewp = Ew + (wid * 32 + l31) * 132;

    auto load_pos = [&](int c_r0, short8* pf) {
#pragma unroll
        for (int et = 0; et < 2; ++et) {
            int r = c_r0 + et * 32 + l31;
            r = min(r, 4094);      // clamped rows land in never-gathered slots
#pragma unroll
            for (int ks = 0; ks < 4; ++ks)
                pf[et * 4 + ks] = *(const short8*)(posg + (size_t)r * 64 + ks * 16 + h * 8);
        }
    };
    // E^T chunk: rows = 64 band slots, cols = t. Ring row shared by h-pair
    // (disjoint slot subsets qd*8 + h4 + j).
    auto e_gemm = [&](const short8* pf, int slotb) {
#pragma unroll
        for (int et = 0; et < 2; ++et) {
            f32x16 ea = zero16();
#pragma unroll
            for (int ks = 0; ks < 4; ++ks)
                ea = mfma_bf(pf[et * 4 + ks], qv_f[ks], ea);
#pragma unroll
            for (int qd = 0; qd < 4; ++qd) {
                f32x4 w;
                w[0] = ea[qd * 4 + 0]; w[1] = ea[qd * 4 + 1];
                w[2] = ea[qd * 4 + 2]; w[3] = ea[qd * 4 + 3];
                *(f32x4*)(ewp + slotb + et * 32 + qd * 8 + h4) = w;
            }
        }
    };

    const int c0 = sc + 1984 - t0;
    {
        short8 pf0[8];
        load_pos(c0, pf0);      e_gemm(pf0, c0 & 127);
        load_pos(c0 + 64, pf0); e_gemm(pf0, (c0 + 64) & 127);
    }

    float m = -3.0e38f, lsum = 0.0f;
    f32x16 o_acc[2];
    o_acc[0] = zero16(); o_acc[1] = zero16();

    const int st_row = threadIdx.x >> 3;     // 0..15 (+16 per rep)
    const int st_q = threadIdx.x & 7;

#pragma unroll 1
    for (int it = 0; it < 16; ++it) {
        const int s0a = sc + it * 64;
        __syncthreads();                  // prior tile reads complete (all waves)
        // ---- stage K[s][dk] and V^T[dk][s] tiles (explicit swizzled ds_write_b128)
#pragma unroll
        for (int rep = 0; rep < 4; ++rep) {
            int row = st_row + rep * 16;
            int off = (row * 128 + st_q * 16) ^ ((row & 7) << 4);
            *(short8*)((char*)Kss + off) =
                *(const short8*)(kg0 + ((size_t)(s0a + row)) * 64 + st_q * 8);
            *(short8*)((char*)Vts + off) =
                *(const short8*)(vtg + (size_t)row * 2048 + s0a + st_q * 8);
        }
        short8 pf[8];
        if (it < 15) load_pos(c0 + 128 + 64 * it, pf);
        unsigned long long mw = mwp[((size_t)(b * 2048 + t)) * 32 + (sc >> 6) + it];
        __syncthreads();                  // staged tiles visible

        // ---- S^T = K . Qu^T
        f32x16 sacc[2];
        sacc[0] = zero16(); sacc[1] = zero16();
#pragma unroll
        for (int st2 = 0; st2 < 2; ++st2)
#pragma unroll
            for (int ks = 0; ks < 4; ++ks) {
                int row = st2 * 32 + l31;
                short8 a = *(const short8*)((char*)Kss +
                    ((row * 128 + ks * 32 + h * 16) ^ ((row & 7) << 4)));
                sacc[st2] = mfma_bf(a, qu_f[ks], sacc[st2]);
            }

        // ---- add banded BD from ring, scale, mask
        const int sb = s0a - t + 2047;
        float sv[32];
#pragma unroll
        for (int st2 = 0; st2 < 2; ++st2)
#pragma unroll
            for (int r = 0; r < 16; ++r) {
                int slot = (sb + st2 * 32 + (r & 3) + ((r >> 2) << 3) + h4) & 127;
                sv[st2 * 16 + r] = (sacc[st2][r] + ewp[slot]) * 0.125f;
            }
        if (__any(mw != 0ull)) {
#pragma unroll
            for (int st2 = 0; st2 < 2; ++st2)
#pragma unroll
                for (int r = 0; r < 16; ++r) {
                    int s_loc = st2 * 32 + (r & 3) + ((r >> 2) << 3) + h4;
                    if ((mw >> s_loc) & 1ull)
                        sv[st2 * 16 + r] = sacc[st2][r] * 0.125f - 100000.0f;
                }
        }

        // ---- online softmax, pair-combined across lane^32
        float mx = sv[0];
#pragma unroll
        for (int i = 1; i < 32; ++i) mx = fmaxf(mx, sv[i]);
        mx = fmaxf(mx, __shfl_xor(mx, 32));
        float mnew = fmaxf(m, mx);
        float alpha = __expf(m - mnew);
        m = mnew;
        float psum = 0.0f;
#pragma unroll
        for (int i = 0; i < 32; ++i) { sv[i] = __expf(sv[i] - mnew); psum += sv[i]; }
        psum += __shfl_xor(psum, 32);
        lsum = lsum * alpha + psum;
        o_acc[0] = o_acc[0] * alpha;
        o_acc[1] = o_acc[1] * alpha;

        // ---- pack P^T into B-fragments (R2-proven symmetric exchange)
        short8 pfrag[4];
#pragma unroll
        for (int st2 = 0; st2 < 2; ++st2) {
            unsigned int X[8];
#pragma unroll
            for (int qd = 0; qd < 4; ++qd) {
                X[qd * 2 + 0] = pack2bf(sv[st2 * 16 + qd * 4 + 0], sv[st2 * 16 + qd * 4 + 1]);
                X[qd * 2 + 1] = pack2bf(sv[st2 * 16 + qd * 4 + 2], sv[st2 * 16 + qd * 4 + 3]);
            }
#pragma unroll
            for (int f = 0; f < 2; ++f) {
                unsigned int a0 = X[4 * f + 0], a1 = X[4 * f + 1];
                unsigned int b0 = X[4 * f + 2], b1 = X[4 * f + 3];
                unsigned int sa0 = (unsigned int)__shfl_xor((int)a0, 32);
                unsigned int sa1 = (unsigned int)__shfl_xor((int)a1, 32);
                unsigned int sb0 = (unsigned int)__shfl_xor((int)b0, 32);
                unsigned int sb1 = (unsigned int)__shfl_xor((int)b1, 32);
                union { unsigned int u[4]; short8 s8; } uu;
                uu.u[0] = h ? sb0 : a0;
                uu.u[1] = h ? sb1 : a1;
                uu.u[2] = h ? b0 : sa0;
                uu.u[3] = h ? b1 : sa1;
                pfrag[st2 * 2 + f] = uu.s8;
            }
        }

        // ---- O^T += V^T . P^T
#pragma unroll
        for (int dkt = 0; dkt < 2; ++dkt)
#pragma unroll
            for (int f = 0; f < 4; ++f) {
                int row = dkt * 32 + l31;
                short8 a = *(const short8*)((char*)Vts +
                    ((row * 128 + f * 32 + h * 16) ^ ((row & 7) << 4)));
                o_acc[dkt] = mfma_bf(a, pfrag[f], o_acc[dkt]);
            }

        // ---- produce next ring chunk (overwrites slots consumed this iter)
        if (it < 15) e_gemm(pf, (c0 + 128 + 64 * it) & 127);
    }

    // ---- epilogue: normalized bf16 partials + stats
    float inv = 1.0f / lsum;
    if (m <= -9.0e4f) inv = 0.0f;
    size_t obase = (((size_t)scb * 16 + bh) * 2048 + t) * 64;
#pragma unroll
    for (int dkt = 0; dkt < 2; ++dkt)
#pragma unroll
        for (int qd = 0; qd < 4; ++qd) {
            int dk0 = dkt * 32 + qd * 8 + h4;
            uint2v u;
            u.x = pack2bf(o_acc[dkt][qd * 4 + 0] * inv, o_acc[dkt][qd * 4 + 1] * inv);
            u.y = pack2bf(o_acc[dkt][qd * 4 + 2] * inv, o_acc[dkt][qd * 4 + 3] * inv);
            *(uint2v*)(opart + obase + dk0) = u;
        }
    if (h == 0) {
        size_t sidx = ((size_t)scb * 16 + bh) * 2048 + t;
        mstat[sidx] = m;
        lstat[sidx] = lsum;
    }
}

// ---------------------------------------------------------------- combine halves
__global__ __launch_bounds__(256) void combine_kernel(
    const unsigned short* __restrict__ opart,
    const float* __restrict__ mstat, const float* __restrict__ lstat,
    unsigned short* __restrict__ attnb)
{
    int idx = blockIdx.x * 256 + threadIdx.x;    // row*64 + dk, row = bh*2048 + t
    int dk = idx & 63, row = idx >> 6;
    int bh = row >> 11, t = row & 2047;
    int b = bh >> 3, head = bh & 7;
    float m0 = mstat[row], m1 = mstat[32768 + row];
    float l0 = lstat[row], l1 = lstat[32768 + row];
    float M = fmaxf(m0, m1);
    float w0 = __expf(m0 - M) * l0, w1 = __expf(m1 - M) * l1;
    float denom = w0 + w1;
    float inv = (denom > 0.0f) ? 1.0f / denom : 0.0f;
    float a0 = w0 * inv, a1 = w1 * inv;
    if (M <= -9.0e4f) { a0 = 0.0f; a1 = 0.0f; }  // fully-masked row -> 0
    float o = a0 * bf2f(opart[(size_t)row * 64 + dk]) +
              a1 * bf2f(opart[(size_t)(32768 + row) * 64 + dk]);
    attnb[((size_t)(b * 2048 + t)) * 512 + head * 64 + dk] = f2bf(o);
}

// ---------------------------------------------------------------- host
extern "C" void kernel_launch(void* const* d_in, const int* in_sizes, int n_in,
                              void* d_out, int out_size, void* d_ws, size_t ws_size,
                              hipStream_t stream) {
    const float* x    = (const float*)d_in[0];
    const float* pe   = (const float*)d_in[1];
    const unsigned char* mask = (const unsigned char*)d_in[2];
    const float* wqkv = (const float*)d_in[3];
    const float* wpos = (const float*)d_in[4];
    const float* wout = (const float*)d_in[5];
    const float* bu   = (const float*)d_in[6];
    const float* bv   = (const float*)d_in[7];
    float* out = (float*)d_out;

    char* ws = (char*)d_ws;
    unsigned short* qu    = (unsigned short*)(ws + 0);
    unsigned short* qv    = (unsigned short*)(ws + 4194304);
    unsigned short* kb    = (unsigned short*)(ws + 8388608);
    unsigned short* vt    = (unsigned short*)(ws + 12582912);
    unsigned short* posb  = (unsigned short*)(ws + 16777216);  // 4,193,280 B
    unsigned long long* maskw = (unsigned long long*)(ws + 20971520);
    unsigned short* opart = (unsigned short*)(ws + 22020096);
    float* mstat          = (float*)(ws + 30408704);
    float* lstat          = (float*)(ws + 30670848);
    unsigned short* attnb = (unsigned short*)(ws + 30932992);
    // total ws use ~33.5 MB, no overlaps

    maskw_kernel<<<512, 256, 0, stream>>>(mask, maskw);
    gemm_bt<0, true, true><<<dim3(12, 32), 256, 0, stream>>>(
        x, wqkv, 4096, qu, qv, kb, vt, nullptr, bu, bv);
    gemm_bt<1, true, true><<<dim3(4, 32), 256, 0, stream>>>(
        pe, wpos, 4095, posb, nullptr, nullptr, nullptr, nullptr, nullptr, nullptr);
    attn_kernel<<<dim3(32, 16, 2), 128, 0, stream>>>(
        qu, qv, kb, vt, posb, maskw, opart, mstat, lstat);
    combine_kernel<<<8192, 256, 0, stream>>>(opart, mstat, lstat, attnb);
    gemm_bt<2, false, true><<<dim3(4, 32), 256, 0, stream>>>(
        attnb, wout, 4096, nullptr, nullptr, nullptr, nullptr, out, nullptr, nullptr);
}